// Round 11
// baseline (473.451 us; speedup 1.0000x reference)
//
#include <hip/hip_runtime.h>
#include <hip/hip_cooperative_groups.h>
#include <math.h>

namespace cg = cooperative_groups;

#define N_TOKENS 4096
#define D_MODEL  1024
#define N_EXPERT 8
#define D_HIDDEN 1024
#define N_POS    8192   // N_TOKENS * TOP_K

typedef __bf16 bf16x8 __attribute__((ext_vector_type(8)));
typedef float  f32x4  __attribute__((ext_vector_type(4)));
typedef unsigned short u16x8 __attribute__((ext_vector_type(8)));

#define GLOBAL_AS __attribute__((address_space(1)))
#define LDS_AS    __attribute__((address_space(3)))

static __device__ __forceinline__ void async_ld16(const void* g, void* l) {
    __builtin_amdgcn_global_load_lds((GLOBAL_AS void*)g, (LDS_AS void*)l, 16, 0, 0);
}

static __device__ __forceinline__ unsigned short f2bf(float f) {
    unsigned int u = __builtin_bit_cast(unsigned int, f);
    u += 0x7fffu + ((u >> 16) & 1u);      // round-to-nearest-even
    return (unsigned short)(u >> 16);
}
static __device__ __forceinline__ unsigned int pack2(float a, float b) {
    return (unsigned int)f2bf(a) | ((unsigned int)f2bf(b) << 16);
}
static __device__ __forceinline__ float bflo(unsigned int u) {
    return __builtin_bit_cast(float, u << 16);
}
static __device__ __forceinline__ float bfhi(unsigned int u) {
    return __builtin_bit_cast(float, u & 0xffff0000u);
}

// ---------------------------------------------------------------------------
// ONE cooperative kernel, 512 blocks x 256 threads (2 blocks/CU guaranteed by
// launch_bounds(256,2) + 25KB LDS). R10's six dispatches summed to ~134us of
// kernel time inside a 224.5us wall — ~90us was inter-dispatch overhead.
// Phases separated by grid.sync():
//   0: weight/inp convert + gate (block-local counts, zero global atomics)
//   1: plan (block 0): prefix sums -> cnts, pos2tok, tok2pos
//   2: ffn1 (R10 tile body, 8 jobs/block, e=bid&7 XCD affinity)
//   3: ffn2
//   4: combine
// No buffer needs zero-init: everything is fully written before it is read.
// ---------------------------------------------------------------------------
__global__ __launch_bounds__(256, 2) void moe_kernel(
    const float* __restrict__ inp, const float* __restrict__ gate_w,
    const float* __restrict__ gate_b, const float* __restrict__ w1,
    const float* __restrict__ b1, const float* __restrict__ w2,
    const float* __restrict__ b2,
    unsigned short* __restrict__ w1b, unsigned short* __restrict__ w2b,
    unsigned short* __restrict__ inp_bf, unsigned short* __restrict__ Hg,
    unsigned short* __restrict__ Og,
    int* __restrict__ gcnt, int* __restrict__ emeta, float* __restrict__ stok,
    int* __restrict__ pos2tok, int* __restrict__ tok2pos,
    int* __restrict__ cnts, float* __restrict__ out)
{
    cg::grid_group grid = cg::this_grid();
    __shared__ __align__(16) char smem[25088];   // union across phases

    int bid = blockIdx.x, tid = threadIdx.x;
    int lane = tid & 63, wave = tid >> 6;
    int lane15 = lane & 15, quad = lane >> 4;

    // ============== Phase 0: convert (jobs 0..5119) + gate (5120..5375) ====
    for (int job = bid; job < 5376; job += 512) {
        if (job < 5120) {
            int mat = job >> 8, t = job & 255;
            int r0 = (t & 15) * 64, c0 = (t >> 4) * 64;
            if (mat >= 16) {           // inp quadrant fp32 -> bf16 copy-cast
                const float* src = inp + (size_t)(mat - 16) * 1048576;
                unsigned short* dst = inp_bf + (size_t)(mat - 16) * 1048576;
                #pragma unroll
                for (int i = 0; i < 4; ++i) {
                    int r = (tid >> 4) + i * 16;
                    float4 v = *(const float4*)(src + (size_t)(r0 + r) * 1024
                                                + c0 + (tid & 15) * 4);
                    uint2 u; u.x = pack2(v.x, v.y); u.y = pack2(v.z, v.w);
                    *(uint2*)(dst + (size_t)(r0 + r) * 1024 + c0 + (tid & 15) * 4) = u;
                }
            } else {                   // weight fp32 -> bf16 transpose [N][K]
                const float* src = (mat < 8) ? (w1 + (size_t)mat * 1048576)
                                             : (w2 + (size_t)(mat - 8) * 1048576);
                unsigned short* dst = (mat < 8) ? (w1b + (size_t)mat * 1048576)
                                                : (w2b + (size_t)(mat - 8) * 1048576);
                float (*tile)[68] = (float(*)[68])smem;   // 64*68*4 = 17408 B
                #pragma unroll
                for (int i = 0; i < 4; ++i) {
                    int r = (tid >> 4) + i * 16;
                    float4 v = *(const float4*)(src + (size_t)(r0 + r) * 1024
                                                + c0 + (tid & 15) * 4);
                    *(float4*)&tile[r][(tid & 15) * 4] = v;
                }
                __syncthreads();
                int dr = tid >> 2;
                #pragma unroll
                for (int p = 0; p < 2; ++p) {
                    int ch = (tid & 3) + p * 4;
                    u16x8 o;
                    #pragma unroll
                    for (int j = 0; j < 8; ++j) o[j] = f2bf(tile[ch * 8 + j][dr]);
                    *(u16x8*)(dst + (size_t)(c0 + dr) * 1024 + r0 + ch * 8) = o;
                }
            }
        } else {
            // ---- gate job g: 16 tokens, fp32-exact top-2 + softmax,
            // block-LOCAL ranks only (gcnt written with plain stores) ----
            int g = job - 5120;
            int* bcnt  = (int*)smem;
            int* tinfo = bcnt + 8;
            if (tid < 8) bcnt[tid] = 0;
            __syncthreads();
            for (int t = 0; t < 4; ++t) {
                int ti = wave * 4 + t;
                int n  = g * 16 + ti;
                const float* ip = inp + (size_t)n * D_MODEL;
                float acc[8] = {0.f,0.f,0.f,0.f,0.f,0.f,0.f,0.f};
                for (int d0 = lane * 4; d0 < D_MODEL; d0 += 256) {
                    float4 x = *(const float4*)(ip + d0);
                    #pragma unroll
                    for (int j = 0; j < 4; ++j) {
                        float xv = (j == 0) ? x.x : (j == 1) ? x.y
                                 : (j == 2) ? x.z : x.w;
                        float4 g0 = *(const float4*)(gate_w + (d0 + j) * 8);
                        float4 g1 = *(const float4*)(gate_w + (d0 + j) * 8 + 4);
                        acc[0] += xv * g0.x; acc[1] += xv * g0.y;
                        acc[2] += xv * g0.z; acc[3] += xv * g0.w;
                        acc[4] += xv * g1.x; acc[5] += xv * g1.y;
                        acc[6] += xv * g1.z; acc[7] += xv * g1.w;
                    }
                }
                #pragma unroll
                for (int off = 32; off > 0; off >>= 1)
                    #pragma unroll
                    for (int e = 0; e < 8; ++e)
                        acc[e] += __shfl_xor(acc[e], off, 64);
                #pragma unroll
                for (int e = 0; e < 8; ++e) acc[e] += gate_b[e];

                // top-2; strictly-greater => lowest index wins ties
                int e0 = 0; float v0 = acc[0];
                #pragma unroll
                for (int e = 1; e < 8; ++e) if (acc[e] > v0) { v0 = acc[e]; e0 = e; }
                int e1 = -1; float v1 = -1e30f;
                #pragma unroll
                for (int e = 0; e < 8; ++e)
                    if (e != e0 && acc[e] > v1) { v1 = acc[e]; e1 = e; }
                float tv = expf(v1 - v0);
                float s0 = 1.0f / (1.0f + tv);
                float s1 = tv / (1.0f + tv);
                if (lane == 0) {
                    int r0 = atomicAdd(&bcnt[e0], 1);
                    int r1 = atomicAdd(&bcnt[e1], 1);
                    tinfo[ti] = e0 | (e1 << 4) | (r0 << 8) | (r1 << 20);
                    stok[2 * n]     = s0;
                    stok[2 * n + 1] = s1;
                }
            }
            __syncthreads();
            if (tid < 8)  gcnt[g * 8 + tid]  = bcnt[tid];
            if (tid < 16) emeta[g * 16 + tid] = tinfo[tid];
        }
        __syncthreads();   // protect smem before next job
    }
    grid.sync();

    // ============== Phase 1: plan (block 0 only) ===========================
    if (bid == 0) {
        int* lc  = (int*)smem;        // gcnt copy      [256][8]
        int* lb  = lc + 2048;         // per-job bases  [256][8]
        int* lex = lb + 2048;         // [0..7]=expert excl offset, [8..15]=totals
        for (int i = tid; i < 2048; i += 256) lc[i] = gcnt[i];
        __syncthreads();
        if (tid < 8) {
            int run = 0;
            for (int g = 0; g < 256; ++g) {
                lb[g * 8 + tid] = run;
                run += lc[g * 8 + tid];
            }
            lex[8 + tid] = run;
            cnts[tid] = run;
        }
        __syncthreads();
        if (tid == 0) {
            int o = 0;
            #pragma unroll
            for (int e = 0; e < 8; ++e) { lex[e] = o; o += lex[8 + e]; }
        }
        __syncthreads();
        {   // thread tid == gate job g: emit both position maps
            int g = tid;
            for (int ti = 0; ti < 16; ++ti) {
                int n = g * 16 + ti;
                unsigned int em = (unsigned int)emeta[n];
                int e0 = em & 15, e1 = (em >> 4) & 15;
                int r0 = (em >> 8) & 4095, r1 = (int)(em >> 20);
                int pos0 = lex[e0] + lb[g * 8 + e0] + r0;
                int pos1 = lex[e1] + lb[g * 8 + e1] + r1;
                tok2pos[2 * n]     = pos0;
                tok2pos[2 * n + 1] = pos1;
                pos2tok[pos0] = n;
                pos2tok[pos1] = n;
            }
        }
    }
    grid.sync();

    // shared tile-job decode for ffn phases (R10 bodies)
    unsigned short* As = (unsigned short*)smem;          // 2*128*32 = 16 KB
    unsigned short* Bs = As + 8192;                      // 2*64*32  =  8 KB
    int* rowtok = (int*)(Bs + 4096);                     // 128 ints

    int lrow = lane >> 2, lchunk = lane & 3;
    int csw8 = (lchunk ^ ((lrow >> 1) & 3)) * 8;
    int wm = (wave & 1) * 64, wn = ((wave >> 1) & 1) * 32;
    int fro = (quad ^ ((lane15 >> 1) & 3)) * 8;

    // ============== Phase 2: ffn1 — Hg[pos]=gelu(inp_bf[tok]@w1b^T+b1) =====
    for (int job = bid; job < 4096; job += 512) {
        int e = job & 7, nt = (job >> 3) & 15, mt = job >> 7;
        int off = 0, Ne = 0;
        #pragma unroll
        for (int i = 0; i < 8; ++i) {
            int c = cnts[i];
            off += (i < e) ? c : 0;
            Ne = (i == e) ? c : Ne;
        }
        int m0 = mt * 128;
        if (m0 >= Ne) continue;
        int n0 = nt * 64;
        __syncthreads();   // protect LDS vs previous job's readers

        if (tid < 128) {
            int r = m0 + tid;
            if (r >= Ne) r = Ne - 1;          // dup last valid; masked at store
            rowtok[tid] = pos2tok[off + r];
        }
        __syncthreads();

        const unsigned short* aS0 =
            inp_bf + (size_t)rowtok[wave * 32 + lrow] * D_MODEL + csw8;
        const unsigned short* aS1 =
            inp_bf + (size_t)rowtok[wave * 32 + 16 + lrow] * D_MODEL + csw8;
        const unsigned short* bS = w1b + (size_t)e * D_MODEL * D_HIDDEN
                                 + (size_t)(n0 + wave * 16 + lrow) * D_MODEL + csw8;
        unsigned short* aD0 = &As[(wave * 32) * 32];
        unsigned short* aD1 = &As[(wave * 32 + 16) * 32];
        unsigned short* bD  = &Bs[(wave * 16) * 32];

        f32x4 acc[4][2] = {};
        for (int k0 = 0; k0 < D_MODEL; k0 += 64) {
            #pragma unroll
            for (int h = 0; h < 2; ++h) {
                int ko = k0 + h * 32;
                async_ld16(aS0 + ko, aD0 + h * 4096);
                async_ld16(aS1 + ko, aD1 + h * 4096);
                async_ld16(bS  + ko, bD  + h * 2048);
            }
            __syncthreads();
            #pragma unroll
            for (int h = 0; h < 2; ++h) {
                bf16x8 af[4], bf[2];
                #pragma unroll
                for (int t = 0; t < 4; ++t)
                    af[t] = *(const bf16x8*)
                        &As[h * 4096 + (wm + t * 16 + lane15) * 32 + fro];
                #pragma unroll
                for (int t = 0; t < 2; ++t)
                    bf[t] = *(const bf16x8*)
                        &Bs[h * 2048 + (wn + t * 16 + lane15) * 32 + fro];
                #pragma unroll
                for (int i = 0; i < 4; ++i)
                    #pragma unroll
                    for (int j = 0; j < 2; ++j)
                        acc[i][j] = __builtin_amdgcn_mfma_f32_16x16x32_bf16(
                            af[i], bf[j], acc[i][j], 0, 0, 0);
            }
            if (k0 + 64 < D_MODEL) __syncthreads();
        }

        const float* bexp = b1 + (size_t)e * D_HIDDEN;
        #pragma unroll
        for (int j = 0; j < 2; ++j) {
            int gcol = n0 + wn + j * 16 + lane15;
            float bv = bexp[gcol];
            #pragma unroll
            for (int i = 0; i < 4; ++i) {
                int rowb = wm + i * 16 + quad * 4;
                #pragma unroll
                for (int r = 0; r < 4; ++r) {
                    int row = rowb + r;
                    if (m0 + row < Ne) {
                        float x = acc[i][j][r] + bv;
                        float gv = 0.5f * x *
                            (1.0f + erff(x * 0.70710678118654752f));
                        Hg[(size_t)(off + m0 + row) * D_HIDDEN + gcol] = f2bf(gv);
                    }
                }
            }
        }
    }
    grid.sync();

    // ============== Phase 3: ffn2 — Og[pos] = Hg[pos] @ w2b^T ==============
    for (int job = bid; job < 4096; job += 512) {
        int e = job & 7, nt = (job >> 3) & 15, mt = job >> 7;
        int off = 0, Ne = 0;
        #pragma unroll
        for (int i = 0; i < 8; ++i) {
            int c = cnts[i];
            off += (i < e) ? c : 0;
            Ne = (i == e) ? c : Ne;
        }
        int m0 = mt * 128;
        if (m0 >= Ne) continue;
        int n0 = nt * 64;
        __syncthreads();

        int ga0 = off + m0 + wave * 32 + lrow;
        int ga1 = ga0 + 16;
        if (ga0 >= N_POS) ga0 = N_POS - 1;
        if (ga1 >= N_POS) ga1 = N_POS - 1;
        const unsigned short* aS0 = Hg + (size_t)ga0 * D_HIDDEN + csw8;
        const unsigned short* aS1 = Hg + (size_t)ga1 * D_HIDDEN + csw8;
        const unsigned short* bS = w2b + (size_t)e * D_HIDDEN * D_MODEL
                                 + (size_t)(n0 + wave * 16 + lrow) * D_HIDDEN + csw8;
        unsigned short* aD0 = &As[(wave * 32) * 32];
        unsigned short* aD1 = &As[(wave * 32 + 16) * 32];
        unsigned short* bD  = &Bs[(wave * 16) * 32];

        f32x4 acc[4][2] = {};
        for (int k0 = 0; k0 < D_HIDDEN; k0 += 64) {
            #pragma unroll
            for (int h = 0; h < 2; ++h) {
                int ko = k0 + h * 32;
                async_ld16(aS0 + ko, aD0 + h * 4096);
                async_ld16(aS1 + ko, aD1 + h * 4096);
                async_ld16(bS  + ko, bD  + h * 2048);
            }
            __syncthreads();
            #pragma unroll
            for (int h = 0; h < 2; ++h) {
                bf16x8 af[4], bf[2];
                #pragma unroll
                for (int t = 0; t < 4; ++t)
                    af[t] = *(const bf16x8*)
                        &As[h * 4096 + (wm + t * 16 + lane15) * 32 + fro];
                #pragma unroll
                for (int t = 0; t < 2; ++t)
                    bf[t] = *(const bf16x8*)
                        &Bs[h * 2048 + (wn + t * 16 + lane15) * 32 + fro];
                #pragma unroll
                for (int i = 0; i < 4; ++i)
                    #pragma unroll
                    for (int j = 0; j < 2; ++j)
                        acc[i][j] = __builtin_amdgcn_mfma_f32_16x16x32_bf16(
                            af[i], bf[j], acc[i][j], 0, 0, 0);
            }
            if (k0 + 64 < D_HIDDEN) __syncthreads();
        }

        #pragma unroll
        for (int j = 0; j < 2; ++j) {
            int gcol = n0 + wn + j * 16 + lane15;
            #pragma unroll
            for (int i = 0; i < 4; ++i) {
                int rowb = wm + i * 16 + quad * 4;
                #pragma unroll
                for (int r = 0; r < 4; ++r) {
                    int row = rowb + r;
                    if (m0 + row < Ne) {
                        Og[(size_t)(off + m0 + row) * D_MODEL + gcol] =
                            f2bf(acc[i][j][r]);
                    }
                }
            }
        }
    }
    grid.sync();

    // ============== Phase 4: combine =======================================
    for (int job = bid; job < 1024; job += 512) {
        int n = job * 4 + wave;
        int pos0 = tok2pos[2 * n], pos1 = tok2pos[2 * n + 1];
        unsigned int em = (unsigned int)emeta[n];
        int e0 = em & 15, e1 = (em >> 4) & 15;
        float s0 = stok[2 * n], s1 = stok[2 * n + 1];
        const unsigned short* o0 = Og + (size_t)pos0 * D_MODEL;
        const unsigned short* o1 = Og + (size_t)pos1 * D_MODEL;
        const float* bA = b2 + (size_t)e0 * D_MODEL;
        const float* bB = b2 + (size_t)e1 * D_MODEL;
        float* op = out + (size_t)n * D_MODEL;
        for (int d = lane * 4; d < D_MODEL; d += 256) {
            uint2 u0 = *(const uint2*)(o0 + d);
            uint2 u1 = *(const uint2*)(o1 + d);
            float4 xa = *(const float4*)(bA + d);
            float4 xb = *(const float4*)(bB + d);
            float4 r;
            r.x = s0 * (bflo(u0.x) + xa.x) + s1 * (bflo(u1.x) + xb.x);
            r.y = s0 * (bfhi(u0.x) + xa.y) + s1 * (bfhi(u1.x) + xb.y);
            r.z = s0 * (bflo(u0.y) + xa.z) + s1 * (bflo(u1.y) + xb.z);
            r.w = s0 * (bfhi(u0.y) + xa.w) + s1 * (bfhi(u1.y) + xb.w);
            *(float4*)(op + d) = r;
        }
    }
}

// ---------------------------------------------------------------------------
extern "C" void kernel_launch(void* const* d_in, const int* in_sizes, int n_in,
                              void* d_out, int out_size, void* d_ws, size_t ws_size,
                              hipStream_t stream) {
    const float* inp    = (const float*)d_in[0];
    const float* gate_w = (const float*)d_in[1];
    const float* gate_b = (const float*)d_in[2];
    const float* w1     = (const float*)d_in[3];
    const float* b1     = (const float*)d_in[4];
    const float* w2     = (const float*)d_in[5];
    const float* b2     = (const float*)d_in[6];
    float* out = (float*)d_out;

    // ws layout (Og aliases w1b — w1b dead after phase 2, Og written phase 3)
    char* ws = (char*)d_ws;
    int*   cnts    = (int*)  (ws);                               // 32 B
    int*   emeta   = (int*)  (ws + 4096);                        // 16 KB
    float* stok    = (float*)(ws + 65536);                       // 32 KB
    int*   pos2tok = (int*)  (ws + 131072);                      // 32 KB
    int*   tok2pos = (int*)  (ws + 196608);                      // 32 KB
    int*   gcnt    = (int*)  (ws + 262144);                      //  8 KB
    unsigned short* w2b = (unsigned short*)(ws + 1048576);       // 16 MiB
    unsigned short* Hg  = (unsigned short*)(ws + 17825792);      // 16 MiB
    unsigned short* w1b = (unsigned short*)(ws + 34603008);      // 16 MiB
    unsigned short* Og  = (unsigned short*)(ws + 34603008);      // aliases w1b
    unsigned short* inp_bf = (unsigned short*)d_out;             // 16 MiB, dead
                                                                 // before phase 4
    void* args[] = {
        (void*)&inp, (void*)&gate_w, (void*)&gate_b, (void*)&w1, (void*)&b1,
        (void*)&w2, (void*)&b2, (void*)&w1b, (void*)&w2b, (void*)&inp_bf,
        (void*)&Hg, (void*)&Og, (void*)&gcnt, (void*)&emeta, (void*)&stok,
        (void*)&pos2tok, (void*)&tok2pos, (void*)&cnts, (void*)&out,
    };
    hipLaunchCooperativeKernel((const void*)moe_kernel, dim3(512), dim3(256),
                               args, 0, stream);
}

// Round 12
// 252.740 us; speedup vs baseline: 1.8733x; 1.8733x over previous
//
#include <hip/hip_runtime.h>
#include <math.h>

#define N_TOKENS 4096
#define D_MODEL  1024
#define N_EXPERT 8
#define D_HIDDEN 1024
#define N_POS    8192   // N_TOKENS * TOP_K

typedef __bf16 bf16x8 __attribute__((ext_vector_type(8)));
typedef float  f32x4  __attribute__((ext_vector_type(4)));
typedef unsigned short u16x8 __attribute__((ext_vector_type(8)));

#define GLOBAL_AS __attribute__((address_space(1)))
#define LDS_AS    __attribute__((address_space(3)))

static __device__ __forceinline__ void async_ld16(const void* g, void* l) {
    __builtin_amdgcn_global_load_lds((GLOBAL_AS void*)g, (LDS_AS void*)l, 16, 0, 0);
}

static __device__ __forceinline__ unsigned short f2bf(float f) {
    unsigned int u = __builtin_bit_cast(unsigned int, f);
    u += 0x7fffu + ((u >> 16) & 1u);      // round-to-nearest-even
    return (unsigned short)(u >> 16);
}
static __device__ __forceinline__ unsigned int pack2(float a, float b) {
    return (unsigned int)f2bf(a) | ((unsigned int)f2bf(b) << 16);
}

// ---------------------------------------------------------------------------
// K1: convert + gate + inline plan (one dispatch).
//   blockIdx 0..255    : gate job (16 tokens, fp32-exact top-2, block-local
//                        ranks, plain gcnt stores). Last gate block to finish
//                        (threadfence + atomicAdd(done)) runs the plan:
//                        prefix sums -> cnts, pos2tok, pos_score.
//   blockIdx 256..5375 : convert tile jobs — w1/w2 fp32->bf16 transposed
//                        [N][K] (mats 0..15) and inp fp32->bf16 copy-cast
//                        into inp_bf = d_out (mats 16..19).
// Gate blocks dispatch first, so the plan hides under remaining converts.
// ---------------------------------------------------------------------------
__global__ __launch_bounds__(256) void prep_kernel(
    const float* __restrict__ inp, const float* __restrict__ gate_w,
    const float* __restrict__ gate_b, const float* __restrict__ w1,
    const float* __restrict__ w2,
    unsigned short* __restrict__ w1b, unsigned short* __restrict__ w2b,
    unsigned short* __restrict__ inp_bf,
    int* __restrict__ gcnt, int* __restrict__ emeta, float* __restrict__ stok,
    int* __restrict__ cnts, int* __restrict__ pos2tok,
    float* __restrict__ pos_score, int* __restrict__ done)
{
    __shared__ __align__(16) char smem[17408];   // convert tile / plan tables
    int job = blockIdx.x, tid = threadIdx.x;

    if (job >= 256) {        // ---------------- convert tile ----------------
        int cj = job - 256;
        int mat = cj >> 8, t = cj & 255;
        int r0 = (t & 15) * 64, c0 = (t >> 4) * 64;
        if (mat >= 16) {     // inp quadrant copy-cast
            const float* src = inp + (size_t)(mat - 16) * 1048576;
            unsigned short* dst = inp_bf + (size_t)(mat - 16) * 1048576;
            #pragma unroll
            for (int i = 0; i < 4; ++i) {
                int r = (tid >> 4) + i * 16;
                float4 v = *(const float4*)(src + (size_t)(r0 + r) * 1024
                                            + c0 + (tid & 15) * 4);
                uint2 u; u.x = pack2(v.x, v.y); u.y = pack2(v.z, v.w);
                *(uint2*)(dst + (size_t)(r0 + r) * 1024 + c0 + (tid & 15) * 4) = u;
            }
        } else {             // weight transpose-cast
            const float* src = (mat < 8) ? (w1 + (size_t)mat * 1048576)
                                         : (w2 + (size_t)(mat - 8) * 1048576);
            unsigned short* dst = (mat < 8) ? (w1b + (size_t)mat * 1048576)
                                            : (w2b + (size_t)(mat - 8) * 1048576);
            float (*tile)[68] = (float(*)[68])smem;
            #pragma unroll
            for (int i = 0; i < 4; ++i) {
                int r = (tid >> 4) + i * 16;
                float4 v = *(const float4*)(src + (size_t)(r0 + r) * 1024
                                            + c0 + (tid & 15) * 4);
                *(float4*)&tile[r][(tid & 15) * 4] = v;
            }
            __syncthreads();
            int dr = tid >> 2;
            #pragma unroll
            for (int p = 0; p < 2; ++p) {
                int ch = (tid & 3) + p * 4;
                u16x8 o;
                #pragma unroll
                for (int j = 0; j < 8; ++j) o[j] = f2bf(tile[ch * 8 + j][dr]);
                *(u16x8*)(dst + (size_t)(c0 + dr) * 1024 + r0 + ch * 8) = o;
            }
        }
        return;
    }

    // ---------------- gate job g = job ----------------
    __shared__ int bcnt[8], tinfo[16], isLast;
    int lane = tid & 63, wave = tid >> 6;
    int g = job;
    if (tid < 8) bcnt[tid] = 0;
    __syncthreads();
    for (int t = 0; t < 4; ++t) {
        int ti = wave * 4 + t;
        int n  = g * 16 + ti;
        const float* ip = inp + (size_t)n * D_MODEL;
        float acc[8] = {0.f,0.f,0.f,0.f,0.f,0.f,0.f,0.f};
        for (int d0 = lane * 4; d0 < D_MODEL; d0 += 256) {
            float4 x = *(const float4*)(ip + d0);
            #pragma unroll
            for (int j = 0; j < 4; ++j) {
                float xv = (j == 0) ? x.x : (j == 1) ? x.y : (j == 2) ? x.z : x.w;
                float4 g0 = *(const float4*)(gate_w + (d0 + j) * 8);
                float4 g1 = *(const float4*)(gate_w + (d0 + j) * 8 + 4);
                acc[0] += xv * g0.x; acc[1] += xv * g0.y;
                acc[2] += xv * g0.z; acc[3] += xv * g0.w;
                acc[4] += xv * g1.x; acc[5] += xv * g1.y;
                acc[6] += xv * g1.z; acc[7] += xv * g1.w;
            }
        }
        #pragma unroll
        for (int off = 32; off > 0; off >>= 1)
            #pragma unroll
            for (int e = 0; e < 8; ++e)
                acc[e] += __shfl_xor(acc[e], off, 64);
        #pragma unroll
        for (int e = 0; e < 8; ++e) acc[e] += gate_b[e];

        // top-2; strictly-greater => lowest index wins ties (lax.top_k)
        int e0 = 0; float v0 = acc[0];
        #pragma unroll
        for (int e = 1; e < 8; ++e) if (acc[e] > v0) { v0 = acc[e]; e0 = e; }
        int e1 = -1; float v1 = -1e30f;
        #pragma unroll
        for (int e = 0; e < 8; ++e)
            if (e != e0 && acc[e] > v1) { v1 = acc[e]; e1 = e; }
        float tv = expf(v1 - v0);
        float s0 = 1.0f / (1.0f + tv);
        float s1 = tv / (1.0f + tv);
        if (lane == 0) {
            int r0 = atomicAdd(&bcnt[e0], 1);
            int r1 = atomicAdd(&bcnt[e1], 1);
            tinfo[ti] = e0 | (e1 << 4) | (r0 << 8) | (r1 << 20);
            stok[2 * n]     = s0;
            stok[2 * n + 1] = s1;
        }
    }
    __syncthreads();
    if (tid < 8)  gcnt[g * 8 + tid]   = bcnt[tid];
    if (tid < 16) emeta[g * 16 + tid] = tinfo[tid];
    __syncthreads();
    if (tid == 0) {
        __threadfence();                         // publish gcnt/emeta/stok
        isLast = (atomicAdd(done, 1) == 255);
    }
    __syncthreads();
    if (!isLast) return;
    __threadfence();                             // acquire other blocks' data

    // ---------------- plan (in the last gate block) ----------------
    int* lc  = (int*)smem;        // gcnt copy      [256][8]
    int* lb  = lc + 2048;         // per-job bases  [256][8]
    int* lex = lb + 2048;         // [0..7]=expert offsets, [8..15]=totals
    for (int i = tid; i < 2048; i += 256) lc[i] = gcnt[i];
    __syncthreads();
    if (tid < 8) {
        int run = 0;
        for (int q = 0; q < 256; ++q) {
            lb[q * 8 + tid] = run;
            run += lc[q * 8 + tid];
        }
        lex[8 + tid] = run;
        cnts[tid] = run;
    }
    __syncthreads();
    if (tid == 0) {
        int o = 0;
        #pragma unroll
        for (int e = 0; e < 8; ++e) { lex[e] = o; o += lex[8 + e]; }
    }
    __syncthreads();
    {   // thread tid == gate job q: scatter position maps
        int q = tid;
        for (int ti = 0; ti < 16; ++ti) {
            int n = q * 16 + ti;
            unsigned int em = (unsigned int)emeta[n];
            int e0 = em & 15, e1 = (em >> 4) & 15;
            int r0 = (em >> 8) & 4095, r1 = (int)(em >> 20);
            int pos0 = lex[e0] + lb[q * 8 + e0] + r0;
            int pos1 = lex[e1] + lb[q * 8 + e1] + r1;
            pos2tok[pos0] = n;  pos_score[pos0] = stok[2 * n];
            pos2tok[pos1] = n;  pos_score[pos1] = stok[2 * n + 1];
        }
    }
}

// ---------------------------------------------------------------------------
// ffn1 (R10-proven): Hg[pos] = gelu( inp_bf[tok(pos)] @ w1b[e]^T + b1[e] )
// 128x64 tile, BK=64, indirect per-lane global_load_lds A-staging.
// ---------------------------------------------------------------------------
__global__ __launch_bounds__(256, 4) void ffn1_kernel(
    const unsigned short* __restrict__ inp_bf, const unsigned short* __restrict__ w1b,
    const float* __restrict__ b1, const int* __restrict__ cnts,
    const int* __restrict__ pos2tok, unsigned short* __restrict__ Hg)
{
    int bid = blockIdx.x;
    int e = bid & 7, nt = (bid >> 3) & 15, mt = bid >> 7;
    int off = 0, Ne = 0;
    #pragma unroll
    for (int i = 0; i < 8; ++i) {
        int c = cnts[i];
        off += (i < e) ? c : 0;
        Ne = (i == e) ? c : Ne;
    }
    int m0 = mt * 128;
    if (m0 >= Ne) return;
    int n0 = nt * 64;

    __shared__ unsigned short As[2 * 128 * 32];
    __shared__ unsigned short Bs[2 * 64 * 32];
    __shared__ int rowtok[128];

    int tid = threadIdx.x, lane = tid & 63, wave = tid >> 6;
    int lrow = lane >> 2, lchunk = lane & 3;
    int csw8 = (lchunk ^ ((lrow >> 1) & 3)) * 8;

    if (tid < 128) {
        int r = m0 + tid;
        if (r >= Ne) r = Ne - 1;
        rowtok[tid] = pos2tok[off + r];
    }
    __syncthreads();

    const unsigned short* aS0 =
        inp_bf + (size_t)rowtok[wave * 32 + lrow] * D_MODEL + csw8;
    const unsigned short* aS1 =
        inp_bf + (size_t)rowtok[wave * 32 + 16 + lrow] * D_MODEL + csw8;
    const unsigned short* bS = w1b + (size_t)e * D_MODEL * D_HIDDEN
                             + (size_t)(n0 + wave * 16 + lrow) * D_MODEL + csw8;
    unsigned short* aD0 = &As[(wave * 32) * 32];
    unsigned short* aD1 = &As[(wave * 32 + 16) * 32];
    unsigned short* bD  = &Bs[(wave * 16) * 32];

    f32x4 acc[4][2] = {};
    int wm = (wave & 1) * 64, wn = ((wave >> 1) & 1) * 32;
    int lane15 = lane & 15, quad = lane >> 4;
    int fro = (quad ^ ((lane15 >> 1) & 3)) * 8;

    for (int k0 = 0; k0 < D_MODEL; k0 += 64) {
        #pragma unroll
        for (int h = 0; h < 2; ++h) {
            int ko = k0 + h * 32;
            async_ld16(aS0 + ko, aD0 + h * 4096);
            async_ld16(aS1 + ko, aD1 + h * 4096);
            async_ld16(bS  + ko, bD  + h * 2048);
        }
        __syncthreads();
        #pragma unroll
        for (int h = 0; h < 2; ++h) {
            bf16x8 af[4], bf[2];
            #pragma unroll
            for (int t = 0; t < 4; ++t)
                af[t] = *(const bf16x8*)&As[h * 4096 + (wm + t * 16 + lane15) * 32 + fro];
            #pragma unroll
            for (int t = 0; t < 2; ++t)
                bf[t] = *(const bf16x8*)&Bs[h * 2048 + (wn + t * 16 + lane15) * 32 + fro];
            #pragma unroll
            for (int i = 0; i < 4; ++i)
                #pragma unroll
                for (int j = 0; j < 2; ++j)
                    acc[i][j] = __builtin_amdgcn_mfma_f32_16x16x32_bf16(
                        af[i], bf[j], acc[i][j], 0, 0, 0);
        }
        if (k0 + 64 < D_MODEL) __syncthreads();
    }

    const float* bexp = b1 + (size_t)e * D_HIDDEN;
    #pragma unroll
    for (int j = 0; j < 2; ++j) {
        int gcol = n0 + wn + j * 16 + lane15;
        float bv = bexp[gcol];
        #pragma unroll
        for (int i = 0; i < 4; ++i) {
            int rowb = wm + i * 16 + quad * 4;
            #pragma unroll
            for (int r = 0; r < 4; ++r) {
                int row = rowb + r;
                if (m0 + row < Ne) {
                    float x = acc[i][j][r] + bv;
                    float gv = 0.5f * x * (1.0f + erff(x * 0.70710678118654752f));
                    Hg[(size_t)(off + m0 + row) * D_HIDDEN + gcol] = f2bf(gv);
                }
            }
        }
    }
}

// ---------------------------------------------------------------------------
// ffn2 with fused combine (R4-verified atomic epilogue + bias folding):
//   out[tok(pos)] += psc[pos] * ( (Hg[pos] @ w2b[e]^T)[col] + b2[e][col] )
// Summed over a token's two positions this reproduces
//   out = sum_p s_p*(H_p@w2 + b2)  exactly. out is pre-zeroed via memset.
// ---------------------------------------------------------------------------
__global__ __launch_bounds__(256, 4) void ffn2_kernel(
    const unsigned short* __restrict__ Hg, const unsigned short* __restrict__ w2b,
    const int* __restrict__ cnts, const int* __restrict__ pos2tok,
    const float* __restrict__ pos_score, const float* __restrict__ b2,
    float* __restrict__ out)
{
    int bid = blockIdx.x;
    int e = bid & 7, nt = (bid >> 3) & 15, mt = bid >> 7;
    int off = 0, Ne = 0;
    #pragma unroll
    for (int i = 0; i < 8; ++i) {
        int c = cnts[i];
        off += (i < e) ? c : 0;
        Ne = (i == e) ? c : Ne;
    }
    int m0 = mt * 128;
    if (m0 >= Ne) return;
    int n0 = nt * 64;

    __shared__ unsigned short As[2 * 128 * 32];
    __shared__ unsigned short Bs[2 * 64 * 32];
    __shared__ int   rowtok[128];
    __shared__ float psc[128];

    int tid = threadIdx.x, lane = tid & 63, wave = tid >> 6;
    int lrow = lane >> 2, lchunk = lane & 3;
    int csw8 = (lchunk ^ ((lrow >> 1) & 3)) * 8;

    if (tid < 128) {
        int r = m0 + tid;
        if (r >= Ne) r = Ne - 1;
        rowtok[tid] = pos2tok[off + r];
        psc[tid]    = pos_score[off + r];
    }
    __syncthreads();

    int ga0 = off + m0 + wave * 32 + lrow;
    int ga1 = ga0 + 16;
    if (ga0 >= N_POS) ga0 = N_POS - 1;
    if (ga1 >= N_POS) ga1 = N_POS - 1;
    const unsigned short* aS0 = Hg + (size_t)ga0 * D_HIDDEN + csw8;
    const unsigned short* aS1 = Hg + (size_t)ga1 * D_HIDDEN + csw8;
    const unsigned short* bS = w2b + (size_t)e * D_HIDDEN * D_MODEL
                             + (size_t)(n0 + wave * 16 + lrow) * D_HIDDEN + csw8;
    unsigned short* aD0 = &As[(wave * 32) * 32];
    unsigned short* aD1 = &As[(wave * 32 + 16) * 32];
    unsigned short* bD  = &Bs[(wave * 16) * 32];

    f32x4 acc[4][2] = {};
    int wm = (wave & 1) * 64, wn = ((wave >> 1) & 1) * 32;
    int lane15 = lane & 15, quad = lane >> 4;
    int fro = (quad ^ ((lane15 >> 1) & 3)) * 8;

    for (int k0 = 0; k0 < D_HIDDEN; k0 += 64) {
        #pragma unroll
        for (int h = 0; h < 2; ++h) {
            int ko = k0 + h * 32;
            async_ld16(aS0 + ko, aD0 + h * 4096);
            async_ld16(aS1 + ko, aD1 + h * 4096);
            async_ld16(bS  + ko, bD  + h * 2048);
        }
        __syncthreads();
        #pragma unroll
        for (int h = 0; h < 2; ++h) {
            bf16x8 af[4], bf[2];
            #pragma unroll
            for (int t = 0; t < 4; ++t)
                af[t] = *(const bf16x8*)&As[h * 4096 + (wm + t * 16 + lane15) * 32 + fro];
            #pragma unroll
            for (int t = 0; t < 2; ++t)
                bf[t] = *(const bf16x8*)&Bs[h * 2048 + (wn + t * 16 + lane15) * 32 + fro];
            #pragma unroll
            for (int i = 0; i < 4; ++i)
                #pragma unroll
                for (int j = 0; j < 2; ++j)
                    acc[i][j] = __builtin_amdgcn_mfma_f32_16x16x32_bf16(
                        af[i], bf[j], acc[i][j], 0, 0, 0);
        }
        if (k0 + 64 < D_HIDDEN) __syncthreads();
    }

    const float* b2e = b2 + (size_t)e * D_MODEL;
    #pragma unroll
    for (int j = 0; j < 2; ++j) {
        int gcol = n0 + wn + j * 16 + lane15;
        float b2v = b2e[gcol];
        #pragma unroll
        for (int i = 0; i < 4; ++i) {
            int rowb = wm + i * 16 + quad * 4;
            #pragma unroll
            for (int r = 0; r < 4; ++r) {
                int row = rowb + r;
                if (m0 + row < Ne) {
                    atomicAdd(&out[(size_t)rowtok[row] * D_MODEL + gcol],
                              psc[row] * (acc[i][j][r] + b2v));
                }
            }
        }
    }
}

// ---------------------------------------------------------------------------
extern "C" void kernel_launch(void* const* d_in, const int* in_sizes, int n_in,
                              void* d_out, int out_size, void* d_ws, size_t ws_size,
                              hipStream_t stream) {
    const float* inp    = (const float*)d_in[0];
    const float* gate_w = (const float*)d_in[1];
    const float* gate_b = (const float*)d_in[2];
    const float* w1     = (const float*)d_in[3];
    const float* b1     = (const float*)d_in[4];
    const float* w2     = (const float*)d_in[5];
    const float* b2     = (const float*)d_in[6];
    float* out = (float*)d_out;

    char* ws = (char*)d_ws;
    int*   cnts      = (int*)  (ws);                             // 32 B
    int*   done      = (int*)  (ws + 128);                       // 4 B
    int*   emeta     = (int*)  (ws + 4096);                      // 16 KB
    float* stok      = (float*)(ws + 65536);                     // 32 KB
    int*   pos2tok   = (int*)  (ws + 131072);                    // 32 KB
    float* pos_score = (float*)(ws + 196608);                    // 32 KB
    int*   gcnt      = (int*)  (ws + 262144);                    //  8 KB
    unsigned short* w2b = (unsigned short*)(ws + 1048576);       // 16 MiB
    unsigned short* Hg  = (unsigned short*)(ws + 17825792);      // 16 MiB
    unsigned short* w1b = (unsigned short*)(ws + 34603008);      // 16 MiB

    // inp_bf lives in d_out; consumed by ffn1, then d_out is zeroed and
    // ffn2 accumulates the final output into it.
    unsigned short* inp_bf = (unsigned short*)d_out;

    hipMemsetAsync(done, 0, sizeof(int), stream);
    prep_kernel<<<dim3(5376), 256, 0, stream>>>(
        inp, gate_w, gate_b, w1, w2, w1b, w2b, inp_bf,
        gcnt, emeta, stok, cnts, pos2tok, pos_score, done);
    ffn1_kernel<<<dim3(4096), 256, 0, stream>>>(
        inp_bf, w1b, b1, cnts, pos2tok, Hg);
    hipMemsetAsync(out, 0, (size_t)N_TOKENS * D_MODEL * sizeof(float), stream);
    ffn2_kernel<<<dim3(4096), 256, 0, stream>>>(
        Hg, w2b, cnts, pos2tok, pos_score, b2, out);
}